// Round 1
// baseline (330.064 us; speedup 1.0000x reference)
//
#include <hip/hip_runtime.h>
#include <math.h>

// Problem constants (B=4, T=256, A=3, C=13, GRID=64, F=18, SCALE=4)
#define NTGT   1024                 // B*T
#define NCAND  (21 * NTGT)          // 7 offsets * 3 anchors * NTGT = 21504
#define NCELL  (4 * 3 * 64 * 64 * 64) // B*A*GRID^3 = 3145728
#define BITW   (NCELL / 32)         // bitmap words = 98304

__device__ __forceinline__ float softplusf(float x) {
    // stable: max(x,0) + log1p(exp(-|x|))
    return fmaxf(x, 0.0f) + log1pf(__expf(-fabsf(x)));
}
__device__ __forceinline__ float sigmoidf(float x) {
    return 1.0f / (1.0f + __expf(-x));
}

// Kernel A: per-candidate bbox/cls loss + tobj bitmap scatter.
// acc[0]=nv_sum, acc[1]=bbox_sum, acc[2]=cls_sum, acc[3]=obj_sum
__global__ __launch_bounds__(256) void cand_kernel(
    const float* __restrict__ p, const float* __restrict__ tg,
    const float* __restrict__ anchor, float* __restrict__ acc,
    unsigned int* __restrict__ bitmap)
{
    int idx = blockIdx.x * 256 + threadIdx.x;
    float nv_v = 0.f, bb_v = 0.f, cl_v = 0.f;
    if (idx < NCAND) {
        int t  = idx & (NTGT - 1);   // target fastest -> coalesced target reads
        int oa = idx >> 10;
        int a  = oa % 3;
        int o  = oa / 3;
        const float* x = tg + t * 18;
        float conf = x[4];
        float rn   = x[3] * 0.25f;           // /SCALE
        float an   = anchor[a] * 0.25f;      // anchor_norm
        float ratio = rn / an;
        bool ok = (conf > 0.5f) && (fmaxf(ratio, 1.0f / ratio) < 4.0f);
        float gv[3] = { x[0] * 0.25f, x[1] * 0.25f, x[2] * 0.25f };
        float off[3] = { 0.f, 0.f, 0.f };
        if (o >= 1) {
            if (o <= 3) {               // m1: frac(g) < 0.5 && g > 1
                int c = o - 1;
                float v = gv[c];
                ok = ok && ((v - floorf(v)) < 0.5f) && (v > 1.0f);
                off[c] = 0.5f;
            } else {                    // m2: frac(64-g) < 0.5 && (64-g) > 1
                int c = o - 4;
                float vi = 64.0f - gv[c];
                ok = ok && ((vi - floorf(vi)) < 0.5f) && (vi > 1.0f);
                off[c] = -0.5f;
            }
        }
        if (ok) {
            float tb[3]; int gq[3];
            #pragma unroll
            for (int c = 0; c < 3; c++) {
                float f = truncf(gv[c] - off[c]);
                tb[c] = gv[c] - f;
                int ii = (int)f;
                gq[c] = min(max(ii, 0), 63);
            }
            int b0 = t >> 8;             // T = 256
            // p[b, a, gk=gq[2], gj=gq[1], gi=gq[0], :]
            unsigned int cell =
                ((((unsigned)(b0 * 3 + a) * 64u + (unsigned)gq[2]) * 64u
                  + (unsigned)gq[1]) * 64u) + (unsigned)gq[0];
            const float* pp = p + (size_t)cell * 18u;
            float pd[18];
            #pragma unroll
            for (int f = 0; f < 18; f++) pd[f] = pp[f];

            float c1[3];
            #pragma unroll
            for (int c = 0; c < 3; c++) c1[c] = sigmoidf(pd[c]) * 2.0f - 0.5f;
            float s4 = sigmoidf(pd[3]) * 2.0f;
            float r1 = s4 * s4 * an;
            float r2 = rn;

            // EIOU
            float h1 = 0.5f * r1, h2 = 0.5f * r2;
            float inter = 1.f, rho2 = 0.f, c2d = 0.f, spen = 0.f;
            float dr2 = (r1 - r2) * (r1 - r2);
            #pragma unroll
            for (int c = 0; c < 3; c++) {
                float lo1 = c1[c] - h1, hi1 = c1[c] + h1;
                float lo2 = tb[c] - h2, hi2 = tb[c] + h2;
                inter *= fmaxf(fminf(hi1, hi2) - fmaxf(lo1, lo2), 0.f);
                float cd  = fmaxf(hi1, hi2) - fminf(lo1, lo2);
                float cd2 = cd * cd;
                float d   = c1[c] - tb[c];
                rho2 += d * d;
                c2d  += cd2;
                spen += dr2 / (cd2 + 1e-7f);
            }
            float uni = r1 * r1 * r1 + r2 * r2 * r2 - inter + 1e-7f;
            float ei  = inter / uni - rho2 / (c2d + 1e-7f) - spen;

            nv_v = 1.0f;
            bb_v = 1.0f - ei;
            float cl = 0.f;
            #pragma unroll
            for (int c = 0; c < 13; c++) {   // bce(l,t) = sp(l) - t*l, t one-hot
                float l = pd[5 + c];
                cl += softplusf(l) - x[5 + c] * l;
            }
            cl_v = cl;
            atomicOr(&bitmap[cell >> 5], 1u << (cell & 31u));
        }
    }
    // wave-64 reduction, one atomic triple per wave
    #pragma unroll
    for (int s = 32; s > 0; s >>= 1) {
        nv_v += __shfl_down(nv_v, s, 64);
        bb_v += __shfl_down(bb_v, s, 64);
        cl_v += __shfl_down(cl_v, s, 64);
    }
    if ((threadIdx.x & 63) == 0 && nv_v != 0.f) {
        atomicAdd(&acc[0], nv_v);
        atomicAdd(&acc[1], bb_v);
        atomicAdd(&acc[2], cl_v);
    }
}

// Kernel B: loss_obj sum over all cells. tobj is binary ->
// bce(p4, t) = softplus(p4) - t*p4.
__global__ __launch_bounds__(256) void obj_kernel(
    const float* __restrict__ p, const unsigned int* __restrict__ bitmap,
    float* __restrict__ acc)
{
    int stride = gridDim.x * blockDim.x;
    float s = 0.f;
    for (int i = blockIdx.x * blockDim.x + threadIdx.x; i < NCELL; i += stride) {
        float l = p[(size_t)i * 18u + 4u];
        unsigned int bit = (bitmap[i >> 5] >> (i & 31)) & 1u;
        s += softplusf(l) - (bit ? l : 0.f);
    }
    #pragma unroll
    for (int sh = 32; sh > 0; sh >>= 1) s += __shfl_down(s, sh, 64);
    __shared__ float sm[4];
    int lane = threadIdx.x & 63, w = threadIdx.x >> 6;
    if (lane == 0) sm[w] = s;
    __syncthreads();
    if (threadIdx.x == 0) {
        atomicAdd(&acc[3], sm[0] + sm[1] + sm[2] + sm[3]);
    }
}

// Kernel C: combine scalars.
__global__ void final_kernel(const float* __restrict__ acc, float* __restrict__ out)
{
    float nv = fmaxf(acc[0], 1.0f);
    float lb = acc[1] / nv;                          // loss_bbox * 1.0
    float lc = acc[2] / (nv * 13.0f) * 10.0f;        // loss_cls  * 10.0
    float lo = acc[3] * (20.0f / (float)NCELL);      // loss_obj  * 20.0
    out[0] = (lb + lo + lc) * 4.0f;                  // * Bs
    out[1] = lo;
    out[2] = lc;
}

extern "C" void kernel_launch(void* const* d_in, const int* in_sizes, int n_in,
                              void* d_out, int out_size, void* d_ws, size_t ws_size,
                              hipStream_t stream) {
    const float* p       = (const float*)d_in[0];
    const float* targets = (const float*)d_in[1];
    const float* anchor  = (const float*)d_in[2];
    float* out = (float*)d_out;

    float* acc = (float*)d_ws;                               // 4 floats
    unsigned int* bitmap = (unsigned int*)((char*)d_ws + 16);

    // zero accumulators + bitmap (ws is poisoned 0xAA before every launch)
    hipMemsetAsync(d_ws, 0, 16 + (size_t)BITW * 4, stream);

    cand_kernel<<<NCAND / 256, 256, 0, stream>>>(p, targets, anchor, acc, bitmap);
    obj_kernel<<<3072, 256, 0, stream>>>(p, bitmap, acc);
    final_kernel<<<1, 1, 0, stream>>>(acc, out);
}

// Round 2
// 310.954 us; speedup vs baseline: 1.0615x; 1.0615x over previous
//
#include <hip/hip_runtime.h>
#include <math.h>

// Problem constants (B=4, T=256, A=3, C=13, GRID=64, F=18, SCALE=4)
#define NTGT   1024                   // B*T
#define NCAND  (21 * NTGT)            // 7 offsets * 3 anchors * NTGT = 21504
#define NCBLK  (NCAND / 256)          // 84 candidate blocks
#define NCELL  (4 * 3 * 64 * 64 * 64) // B*A*GRID^3 = 3145728
#define BITW   (NCELL / 32)           // bitmap words = 98304
#define NBLK   2048                   // streaming grid (fills 256 CUs at 8 blk/CU)

// acc layout: [0]=nv, [1]=bbox, [2]=cls, [3]=softplus_sum, [4]=claimed_p4_sum
__device__ __forceinline__ float softplusf(float x) {
    // max(x,0) + log(1 + exp(-|x|)); |err| ~ulp, threshold is 2.08 absolute
    return fmaxf(x, 0.0f) + __logf(1.0f + __expf(-fabsf(x)));
}
__device__ __forceinline__ float sigmoidf(float x) {
    return 1.0f / (1.0f + __expf(-x));
}

__global__ __launch_bounds__(256) void fused_kernel(
    const float* __restrict__ p, const float* __restrict__ tg,
    const float* __restrict__ anchor, float* __restrict__ acc,
    unsigned int* __restrict__ bitmap)
{
    // ---- Part 1: candidate bbox/cls + occupancy claim (blocks 0..83) ----
    if (blockIdx.x < NCBLK) {
        int idx = blockIdx.x * 256 + threadIdx.x;
        float nv_v = 0.f, bb_v = 0.f, cl_v = 0.f, ob_v = 0.f;
        {
            int t  = idx & (NTGT - 1);   // target fastest -> coalesced tg reads
            int oa = idx >> 10;
            int a  = oa % 3;
            int o  = oa / 3;
            const float* x = tg + t * 18;
            float conf = x[4];
            float rn   = x[3] * 0.25f;           // r / SCALE
            float an   = anchor[a] * 0.25f;      // anchor_norm
            float ratio = rn / an;
            bool ok = (conf > 0.5f) && (fmaxf(ratio, 1.0f / ratio) < 4.0f);
            float gv[3] = { x[0] * 0.25f, x[1] * 0.25f, x[2] * 0.25f };
            float off[3] = { 0.f, 0.f, 0.f };
            if (o >= 1) {
                if (o <= 3) {               // m1: frac(g) < 0.5 && g > 1
                    int c = o - 1;
                    float v = gv[c];
                    ok = ok && ((v - floorf(v)) < 0.5f) && (v > 1.0f);
                    off[c] = 0.5f;
                } else {                    // m2: frac(64-g) < 0.5 && (64-g) > 1
                    int c = o - 4;
                    float vi = 64.0f - gv[c];
                    ok = ok && ((vi - floorf(vi)) < 0.5f) && (vi > 1.0f);
                    off[c] = -0.5f;
                }
            }
            if (ok) {
                float tb[3]; int gq[3];
                #pragma unroll
                for (int c = 0; c < 3; c++) {
                    float f = truncf(gv[c] - off[c]);
                    tb[c] = gv[c] - f;
                    gq[c] = min(max((int)f, 0), 63);
                }
                int b0 = t >> 8;             // T = 256
                unsigned int cell =
                    ((((unsigned)(b0 * 3 + a) * 64u + (unsigned)gq[2]) * 64u
                      + (unsigned)gq[1]) * 64u) + (unsigned)gq[0];
                const float* pp = p + (size_t)cell * 18u;
                float pd[18];
                #pragma unroll
                for (int f = 0; f < 18; f++) pd[f] = pp[f];

                float c1[3];
                #pragma unroll
                for (int c = 0; c < 3; c++) c1[c] = sigmoidf(pd[c]) * 2.0f - 0.5f;
                float s4 = sigmoidf(pd[3]) * 2.0f;
                float r1 = s4 * s4 * an;
                float r2 = rn;

                // EIOU
                float h1 = 0.5f * r1, h2 = 0.5f * r2;
                float inter = 1.f, rho2 = 0.f, c2d = 0.f, spen = 0.f;
                float dr2 = (r1 - r2) * (r1 - r2);
                #pragma unroll
                for (int c = 0; c < 3; c++) {
                    float lo1 = c1[c] - h1, hi1 = c1[c] + h1;
                    float lo2 = tb[c] - h2, hi2 = tb[c] + h2;
                    inter *= fmaxf(fminf(hi1, hi2) - fmaxf(lo1, lo2), 0.f);
                    float cd  = fmaxf(hi1, hi2) - fminf(lo1, lo2);
                    float cd2 = cd * cd;
                    float d   = c1[c] - tb[c];
                    rho2 += d * d;
                    c2d  += cd2;
                    spen += dr2 / (cd2 + 1e-7f);
                }
                float uni = r1 * r1 * r1 + r2 * r2 * r2 - inter + 1e-7f;
                float ei  = inter / uni - rho2 / (c2d + 1e-7f) - spen;

                nv_v = 1.0f;
                bb_v = 1.0f - ei;
                float cl = 0.f;
                #pragma unroll
                for (int c = 0; c < 13; c++) {   // bce(l,t)=sp(l)-t*l, t one-hot
                    float l = pd[5 + c];
                    cl += softplusf(l) - x[5 + c] * l;
                }
                cl_v = cl;
                // claim: first valid candidate on this cell contributes p4 once
                unsigned int old = atomicOr(&bitmap[cell >> 5], 1u << (cell & 31u));
                if (!(old & (1u << (cell & 31u)))) ob_v = pd[4];
            }
        }
        #pragma unroll
        for (int s = 32; s > 0; s >>= 1) {
            nv_v += __shfl_down(nv_v, s, 64);
            bb_v += __shfl_down(bb_v, s, 64);
            cl_v += __shfl_down(cl_v, s, 64);
            ob_v += __shfl_down(ob_v, s, 64);
        }
        if ((threadIdx.x & 63) == 0 && nv_v != 0.f) {
            atomicAdd(&acc[0], nv_v);
            atomicAdd(&acc[1], bb_v);
            atomicAdd(&acc[2], cl_v);
            atomicAdd(&acc[4], ob_v);
        }
    }

    // ---- Part 2: streaming softplus reduction over all cells' p4 ----
    float s = 0.f;
    {
        int i = blockIdx.x * 256 + threadIdx.x;
        // NCELL / (NBLK*256) = 6 iterations, fully uniform (no tail)
        #pragma unroll
        for (int it = 0; it < NCELL / (NBLK * 256); it++) {
            s += softplusf(p[(size_t)i * 18u + 4u]);
            i += NBLK * 256;
        }
    }
    #pragma unroll
    for (int sh = 32; sh > 0; sh >>= 1) s += __shfl_down(s, sh, 64);
    __shared__ float sm[4];
    int lane = threadIdx.x & 63, w = threadIdx.x >> 6;
    if (lane == 0) sm[w] = s;
    __syncthreads();
    if (threadIdx.x == 0) {
        atomicAdd(&acc[3], sm[0] + sm[1] + sm[2] + sm[3]);
    }
}

// combine scalars: lo = (softplus_sum - claimed_p4_sum) * 20 / NCELL
__global__ void final_kernel(const float* __restrict__ acc, float* __restrict__ out)
{
    float nv = fmaxf(acc[0], 1.0f);
    float lb = acc[1] / nv;                               // loss_bbox * 1.0
    float lc = acc[2] / (nv * 13.0f) * 10.0f;             // loss_cls  * 10.0
    float lo = (acc[3] - acc[4]) * (20.0f / (float)NCELL);
    out[0] = (lb + lo + lc) * 4.0f;                       // * Bs
    out[1] = lo;
    out[2] = lc;
}

extern "C" void kernel_launch(void* const* d_in, const int* in_sizes, int n_in,
                              void* d_out, int out_size, void* d_ws, size_t ws_size,
                              hipStream_t stream) {
    const float* p       = (const float*)d_in[0];
    const float* targets = (const float*)d_in[1];
    const float* anchor  = (const float*)d_in[2];
    float* out = (float*)d_out;

    float* acc = (float*)d_ws;                               // 8 floats
    unsigned int* bitmap = (unsigned int*)((char*)d_ws + 32);

    // zero accumulators + claim-bitmap (ws is poisoned 0xAA before every launch)
    hipMemsetAsync(d_ws, 0, 32 + (size_t)BITW * 4, stream);

    fused_kernel<<<NBLK, 256, 0, stream>>>(p, targets, anchor, acc, bitmap);
    final_kernel<<<1, 1, 0, stream>>>(acc, out);
}